// Round 1
// 59.723 us; speedup vs baseline: 1.0107x; 1.0107x over previous
//
#include <hip/hip_runtime.h>

// Problem: out[b] = w_bias + sum_{s=0}^{199} w_weight[ text[s][b] ]
//   text: (S=200, B=2048) int32 in [0, 50000); w: (50000,) f32; out: (2048,) f32
//
// v2 strategy: SINGLE dispatch, no atomics, no memset.
//   - Each block owns 8 b-values end-to-end: 256 threads = 8 b x 32 s-chunks
//     (chunk c covers s in [floor(c*6.25), floor((c+1)*6.25)) -> 6 or 7 values).
//   - Grid = 2048/8 = 256 blocks -> exactly 1 block per CU, all CUs busy
//     (vs 200 blocks/0.78 waves-per-SIMD before), ~7 independent gathers of
//     ILP per thread to hide L2 gather latency.
//   - 32-way per-b reduction through 1 KB of LDS, then a direct coalesced
//     store of sum+bias. Since no cross-block accumulation touches out, the
//     0xAA poison doesn't matter and the hipMemsetAsync dispatch is gone.

#define VV 50000
#define SS 200
#define BB 2048
#define NB 8        // b-values per block
#define NCHUNK 32   // s-chunks per block (NB * NCHUNK = 256 threads)
#define MAXC 7      // ceil(SS / NCHUNK)

__global__ __launch_bounds__(256) void MNB_455266533601_kernel(
    const int* __restrict__ text,
    const float* __restrict__ w,
    const float* __restrict__ bias,
    float* __restrict__ out)
{
    const int tid = threadIdx.x;
    const int bl  = tid & (NB - 1);      // b within block: 0..7
    const int c   = tid >> 3;            // s-chunk: 0..31
    const int b   = blockIdx.x * NB + bl;
    const int s0  = (c * SS) >> 5;       // floor(c * 200/32), exact
    const int s1  = ((c + 1) * SS) >> 5;

    float sum = 0.0f;
#pragma unroll
    for (int k = 0; k < MAXC; ++k) {     // predicated full unroll: all text
        const int s = s0 + k;            // loads issue up front, gathers
        if (s < s1)                      // pipeline behind them
            sum += w[text[s * BB + b]];  // text: coalesced 32B/8-lane group
    }

    __shared__ float part[NCHUNK][NB];   // 1 KB; write addr == tid -> conflict-free
    part[c][bl] = sum;
    __syncthreads();

    if (tid < NB) {
        float t = bias[0];
#pragma unroll
        for (int cc = 0; cc < NCHUNK; ++cc)
            t += part[cc][bl];
        out[b] = t;                      // direct store: poison overwritten
    }
}

extern "C" void kernel_launch(void* const* d_in, const int* in_sizes, int n_in,
                              void* d_out, int out_size, void* d_ws, size_t ws_size,
                              hipStream_t stream) {
    const int*   text = (const int*)  d_in[0];   // 409600 elements
    const float* w    = (const float*)d_in[1];   // 50000
    const float* bias = (const float*)d_in[2];   // 1
    float* out = (float*)d_out;                  // 2048

    dim3 grid(BB / NB, 1, 1);   // 256 blocks -> one per CU
    dim3 block(NB * NCHUNK, 1, 1);
    MNB_455266533601_kernel<<<grid, block, 0, stream>>>(text, w, bias, out);
}